// Round 1
// baseline (523.158 us; speedup 1.0000x reference)
//
#include <hip/hip_runtime.h>

// Problem constants (B, D, T, V) = (16, 128, 4096, 1024)
#define B_ 16
#define D_ 128
#define T_ 4096
#define V_ 1024

// Pre-kernel: chsq[v] = 0.5 * sum_d codebook[v][d]^2  (argmin(d2) == argmin(chsq[v] - x.c))
__global__ __launch_bounds__(256) void csq_half_kernel(const float* __restrict__ cb,
                                                       float* __restrict__ chsq) {
    const int v = blockIdx.x * 256 + threadIdx.x;
    const float4* row = reinterpret_cast<const float4*>(cb + (size_t)v * D_);
    float s0 = 0.f, s1 = 0.f, s2 = 0.f, s3 = 0.f;
#pragma unroll
    for (int i = 0; i < D_ / 4; ++i) {
        float4 c = row[i];
        s0 = fmaf(c.x, c.x, s0);
        s1 = fmaf(c.y, c.y, s1);
        s2 = fmaf(c.z, c.z, s2);
        s3 = fmaf(c.w, c.w, s3);
    }
    chsq[v] = 0.5f * ((s0 + s1) + (s2 + s3));
}

// Main kernel: block = 256 threads = 4 waves.
//  - lane (tid&63) <-> t-position within a 64-wide t-tile
//  - wave (tid>>6) <-> quarter of the codebook [q*256, q*256+256)
//  - x row (128 floats) lives in VGPRs; codebook rows are wave-uniform loads
//  - LDS reduce across quarters (strict <, ascending v => numpy-style first-index ties)
//  - fused gather: write quantized (D x 64t) tile with coalesced stores
__global__ __launch_bounds__(256) void vq_kernel(const float* __restrict__ latents,
                                                 const float* __restrict__ codebook,
                                                 const float* __restrict__ chsq,
                                                 float* __restrict__ out_codes,
                                                 float* __restrict__ out_q) {
    const int tid = threadIdx.x;
    const int tl = tid & 63;
    const int q = __builtin_amdgcn_readfirstlane(tid >> 6);  // wave-uniform quarter id
    const int bid = blockIdx.x;
    const int b = bid >> 6;          // 64 t-tiles per batch entry
    const int t0 = (bid & 63) << 6;  // t-tile start

    // Load x[d] = latents[b, d, t0+tl] into registers (coalesced across lanes per d).
    float xr[D_];
    {
        const float* xp = latents + (size_t)b * D_ * T_ + t0 + tl;
#pragma unroll
        for (int d = 0; d < D_; ++d) xr[d] = xp[(size_t)d * T_];
    }

    float best = 3.0e38f;
    int bestv = 0;
    const int v0 = q * (V_ / 4);
    for (int vi = 0; vi < V_ / 4; ++vi) {
        const int v = v0 + vi;  // wave-uniform
        const float4* crow = reinterpret_cast<const float4*>(codebook + (size_t)v * D_);
        float a0 = 0.f, a1 = 0.f, a2 = 0.f, a3 = 0.f;
#pragma unroll
        for (int i = 0; i < D_ / 4; ++i) {
            float4 c = crow[i];  // wave-uniform address -> broadcast / scalarizable
            a0 = fmaf(c.x, xr[4 * i + 0], a0);
            a1 = fmaf(c.y, xr[4 * i + 1], a1);
            a2 = fmaf(c.z, xr[4 * i + 2], a2);
            a3 = fmaf(c.w, xr[4 * i + 3], a3);
        }
        const float score = chsq[v] - ((a0 + a1) + (a2 + a3));
        if (score < best) {  // strict < keeps the lowest v on exact ties
            best = score;
            bestv = v;
        }
    }

    __shared__ float sb[4][64];
    __shared__ int si[4][64];
    __shared__ int fcode[64];
    sb[q][tl] = best;
    si[q][tl] = bestv;
    __syncthreads();

    if (tid < 64) {
        float bb = sb[0][tl];
        int bv = si[0][tl];
#pragma unroll
        for (int qq = 1; qq < 4; ++qq) {
            const float ob = sb[qq][tl];
            const int ov = si[qq][tl];
            if (ob < bb) {  // quarters ascend in v; strict < => lowest v on ties
                bb = ob;
                bv = ov;
            }
        }
        fcode[tl] = bv;
        // codes output, written as float32 values (harness reads d_out as one f32 buffer)
        out_codes[(size_t)b * T_ + t0 + tl] = (float)bv;
    }
    __syncthreads();

    // Gather-write quantized[b, d, t0+tl] = codebook[code[t], d].
    // Lanes within a wave share d and walk consecutive t -> coalesced 256B stores.
    const int c = fcode[tl];
    const int dq = tid >> 6;
    const float* crow = codebook + (size_t)c * D_;
    float* qp = out_q + (size_t)b * D_ * T_ + t0 + tl;
#pragma unroll
    for (int i = 0; i < 32; ++i) {
        const int d = dq * 32 + i;
        qp[(size_t)d * T_] = crow[d];
    }
}

extern "C" void kernel_launch(void* const* d_in, const int* in_sizes, int n_in,
                              void* d_out, int out_size, void* d_ws, size_t ws_size,
                              hipStream_t stream) {
    const float* latents = (const float*)d_in[0];   // (B, D, T) f32
    const float* codebook = (const float*)d_in[1];  // (V, D) f32

    float* out_codes = (float*)d_out;            // (B, T) codes as f32 values
    float* out_q = (float*)d_out + B_ * T_;      // (B, D, T) quantized f32
    float* chsq = (float*)d_ws;                  // V floats of scratch

    csq_half_kernel<<<V_ / 256, 256, 0, stream>>>(codebook, chsq);
    vq_kernel<<<(B_ * T_) / 64, 256, 0, stream>>>(latents, codebook, chsq, out_codes, out_q);
}

// Round 2
// 182.782 us; speedup vs baseline: 2.8622x; 2.8622x over previous
//
#include <hip/hip_runtime.h>

// (B, D, T, V) = (16, 128, 4096, 1024)
#define B_ 16
#define D_ 128
#define T_ 4096
#define V_ 1024

typedef _Float16 half8 __attribute__((ext_vector_type(8)));
typedef float float4v __attribute__((ext_vector_type(4)));

// ws layout:
//   [0,       4096)   : chsq  (V floats)  = 0.5*|c|^2
//   [4096,  266240)   : Bh    (4 kt x 1024 v x 32 kk) f16 hi split, MFMA-B-ready
//   [266240,528384)   : Bl    (same, lo split scaled by 2048)

__global__ __launch_bounds__(256) void csq_half_kernel(const float* __restrict__ cb,
                                                       float* __restrict__ chsq) {
    const int v = blockIdx.x * 256 + threadIdx.x;
    const float4* row = reinterpret_cast<const float4*>(cb + (size_t)v * D_);
    float s0 = 0.f, s1 = 0.f, s2 = 0.f, s3 = 0.f;
#pragma unroll
    for (int i = 0; i < D_ / 4; ++i) {
        float4 c = row[i];
        s0 = fmaf(c.x, c.x, s0);
        s1 = fmaf(c.y, c.y, s1);
        s2 = fmaf(c.z, c.z, s2);
        s3 = fmaf(c.w, c.w, s3);
    }
    chsq[v] = 0.5f * ((s0 + s1) + (s2 + s3));
}

// Split codebook into f16 hi/lo (lo scaled by 2048) in MFMA-B fragment layout:
//   Bx[((kt*V + v)*32) + kk] = split(codebook[v][kt*32+kk])
// so a B-fragment (n-tile of 16, k-tile of 32) is one coalesced dwordx4 per lane.
__global__ __launch_bounds__(256) void split_kernel(const float* __restrict__ cb,
                                                    _Float16* __restrict__ Bh,
                                                    _Float16* __restrict__ Bl) {
    const int g = blockIdx.x * 256 + threadIdx.x;  // 16384 threads
    const int v = g >> 4;
    const int k0 = (g & 15) << 3;
    const float* src = cb + (size_t)v * D_ + k0;
    half8 h, l;
#pragma unroll
    for (int j = 0; j < 8; ++j) {
        float c = src[j];
        _Float16 ch = (_Float16)c;
        h[j] = ch;
        l[j] = (_Float16)((c - (float)ch) * 2048.0f);
    }
    const int kt = k0 >> 5;
    const int kk = k0 & 31;
    const size_t off = ((size_t)(kt * V_ + v)) * 32 + kk;
    *(half8*)(Bh + off) = h;
    *(half8*)(Bl + off) = l;
}

// Main kernel: block = 256 thr = 4 waves; block tile = 64 t x all 1024 v.
//  - A (x hi/lo f16) staged once in LDS, padded rows (136 halves) -> conflict-free b128
//  - wave w sweeps v in [w*256, w*256+256) in chunks of 32 (2 n-tiles), mt=4
//  - dual accumulators: acc1 = xh*ch ; acc2 = xh*cl' + xl'*ch (lo scaled 2048)
//  - score = 0.5|c|^2 - (acc1 + acc2/2048); running argmin, strict < ascending v
__global__ __launch_bounds__(256, 2) void vq_mfma(const float* __restrict__ latents,
                                                  const float* __restrict__ codebook,
                                                  const float* __restrict__ chsq,
                                                  const _Float16* __restrict__ Bh,
                                                  const _Float16* __restrict__ Bl,
                                                  float* __restrict__ out_codes,
                                                  float* __restrict__ out_q) {
    __shared__ _Float16 Ah[64][136];
    __shared__ _Float16 Al[64][136];
    __shared__ float sbest[4][64];
    __shared__ int sbv[4][64];
    __shared__ int scode[64];

    const int tid = threadIdx.x;
    const int tl = tid & 63;
    const int wq = tid >> 6;
    const int b = blockIdx.x >> 6;
    const int t00 = (blockIdx.x & 63) << 6;

    // ---- stage A tile (64 t x 128 d), f16 split, transposed into [t][k] rows ----
    {
        const float* xp = latents + (size_t)b * D_ * T_ + t00 + tl;
#pragma unroll
        for (int i = 0; i < 4; ++i) {
            const int d0 = wq * 32 + i * 8;
            float x[8];
#pragma unroll
            for (int j = 0; j < 8; ++j) x[j] = xp[(size_t)(d0 + j) * T_];
            half8 h, l;
#pragma unroll
            for (int j = 0; j < 8; ++j) {
                _Float16 xh = (_Float16)x[j];
                h[j] = xh;
                l[j] = (_Float16)((x[j] - (float)xh) * 2048.0f);
            }
            *(half8*)&Ah[tl][d0] = h;
            *(half8*)&Al[tl][d0] = l;
        }
    }
    __syncthreads();

    const int ln = tid & 15;  // MFMA col (n) / A row (m)
    const int q = (tid >> 4) & 3;  // quad

    float best[4][4];
    int bestv[4][4];
#pragma unroll
    for (int mt = 0; mt < 4; ++mt)
#pragma unroll
        for (int r = 0; r < 4; ++r) {
            best[mt][r] = 3.0e38f;
            bestv[mt][r] = 0;
        }

    for (int c = 0; c < 8; ++c) {
        const int n0 = wq * 256 + c * 32;
        float4v acc1[4][2], acc2[4][2];
#pragma unroll
        for (int mt = 0; mt < 4; ++mt)
#pragma unroll
            for (int ntl = 0; ntl < 2; ++ntl) {
                acc1[mt][ntl] = (float4v){0.f, 0.f, 0.f, 0.f};
                acc2[mt][ntl] = (float4v){0.f, 0.f, 0.f, 0.f};
            }
#pragma unroll
        for (int kt = 0; kt < 4; ++kt) {
            half8 ah[4], al[4];
#pragma unroll
            for (int mt = 0; mt < 4; ++mt) {
                ah[mt] = *(const half8*)&Ah[mt * 16 + ln][kt * 32 + q * 8];
                al[mt] = *(const half8*)&Al[mt * 16 + ln][kt * 32 + q * 8];
            }
#pragma unroll
            for (int ntl = 0; ntl < 2; ++ntl) {
                const size_t boff = ((size_t)(kt * V_ + n0 + ntl * 16 + ln)) * 32 + q * 8;
                const half8 bh = *(const half8*)(Bh + boff);
                const half8 bl = *(const half8*)(Bl + boff);
#pragma unroll
                for (int mt = 0; mt < 4; ++mt)
                    acc1[mt][ntl] =
                        __builtin_amdgcn_mfma_f32_16x16x32_f16(ah[mt], bh, acc1[mt][ntl], 0, 0, 0);
#pragma unroll
                for (int mt = 0; mt < 4; ++mt)
                    acc2[mt][ntl] =
                        __builtin_amdgcn_mfma_f32_16x16x32_f16(ah[mt], bl, acc2[mt][ntl], 0, 0, 0);
#pragma unroll
                for (int mt = 0; mt < 4; ++mt)
                    acc2[mt][ntl] =
                        __builtin_amdgcn_mfma_f32_16x16x32_f16(al[mt], bh, acc2[mt][ntl], 0, 0, 0);
            }
        }
        // fold chunk scores into running argmin (ntl=0 first: lower n wins ties)
#pragma unroll
        for (int ntl = 0; ntl < 2; ++ntl) {
            const int n = n0 + ntl * 16 + ln;
            const float csq = chsq[n];
#pragma unroll
            for (int mt = 0; mt < 4; ++mt)
#pragma unroll
                for (int r = 0; r < 4; ++r) {
                    const float score =
                        csq - (acc1[mt][ntl][r] + acc2[mt][ntl][r] * (1.0f / 2048.0f));
                    if (score < best[mt][r]) {
                        best[mt][r] = score;
                        bestv[mt][r] = n;
                    }
                }
        }
    }

    // cross-lane argmin over the 16-col group (lane bits 0..3); ties -> lowest v
#pragma unroll
    for (int off = 1; off < 16; off <<= 1) {
#pragma unroll
        for (int mt = 0; mt < 4; ++mt)
#pragma unroll
            for (int r = 0; r < 4; ++r) {
                const float ob = __shfl_xor(best[mt][r], off, 64);
                const int ov = __shfl_xor(bestv[mt][r], off, 64);
                if (ob < best[mt][r] || (ob == best[mt][r] && ov < bestv[mt][r])) {
                    best[mt][r] = ob;
                    bestv[mt][r] = ov;
                }
            }
    }

    if (ln == 0) {
#pragma unroll
        for (int mt = 0; mt < 4; ++mt)
#pragma unroll
            for (int r = 0; r < 4; ++r) {
                const int m = mt * 16 + q * 4 + r;
                sbest[wq][m] = best[mt][r];
                sbv[wq][m] = bestv[mt][r];
            }
    }
    __syncthreads();

    if (tid < 64) {
        float bb = sbest[0][tid];
        int bv = sbv[0][tid];
#pragma unroll
        for (int w = 1; w < 4; ++w) {
            const float ob = sbest[w][tid];
            const int ov = sbv[w][tid];
            if (ob < bb) {  // waves ascend in v; strict < keeps lowest v on ties
                bb = ob;
                bv = ov;
            }
        }
        scode[tid] = bv;
        out_codes[(size_t)b * T_ + t00 + tid] = (float)bv;
    }
    __syncthreads();

    // gather-write quantized[b, d, t00+tl] = codebook[code, d]; coalesced stores
    const int code = scode[tl];
    const float* crow = codebook + (size_t)code * D_;
    float* qp = out_q + (size_t)b * D_ * T_ + t00 + tl;
#pragma unroll
    for (int i = 0; i < 32; ++i) {
        const int d = wq * 32 + i;
        qp[(size_t)d * T_] = crow[d];
    }
}

extern "C" void kernel_launch(void* const* d_in, const int* in_sizes, int n_in,
                              void* d_out, int out_size, void* d_ws, size_t ws_size,
                              hipStream_t stream) {
    const float* latents = (const float*)d_in[0];   // (B, D, T) f32
    const float* codebook = (const float*)d_in[1];  // (V, D) f32

    float* out_codes = (float*)d_out;        // (B, T) codes as f32 values
    float* out_q = (float*)d_out + B_ * T_;  // (B, D, T) quantized f32

    float* chsq = (float*)d_ws;
    _Float16* Bh = (_Float16*)((char*)d_ws + 4096);
    _Float16* Bl = (_Float16*)((char*)d_ws + 4096 + 262144);

    csq_half_kernel<<<V_ / 256, 256, 0, stream>>>(codebook, chsq);
    split_kernel<<<(V_ * 16) / 256, 256, 0, stream>>>(codebook, Bh, Bl);
    vq_mfma<<<(B_ * T_) / 64, 256, 0, stream>>>(latents, codebook, chsq, Bh, Bl, out_codes,
                                                out_q);
}